// Round 11
// baseline (393.990 us; speedup 1.0000x reference)
//
#include <hip/hip_runtime.h>
#include <hip/hip_cooperative_groups.h>

namespace cg = cooperative_groups;

#define H_DIM 768
#define B_DIM 64
#define L_DIM 512
#define M_TOT (B_DIM*L_DIM)   // 32768
#define BM 128
#define BN 128
#define BK 64
#define NB_CNT (H_DIM/BN)     // 6
#define KB_CNT (H_DIM/BK)     // 12
#define MB_CNT (M_TOT/BM)     // 256
#define TILE_HALFS (BM*BK)    // 8192 halfs = 16KB
#define BUFH 16384            // halfs per LDS buffer (A 8192 + B 8192 = 32KB)

typedef _Float16 f16x8 __attribute__((ext_vector_type(8)));
typedef float f32x4 __attribute__((ext_vector_type(4)));

// ws byte offsets
#define WS_W16   0u           // 768*768 halfs (tiled, swizzle-baked)
#define WS_NUP   1179648u     // 6*32768 f32
#define WS_POOL  2097152u     // 8*64*768 f32
#define WS_AIMG  3670016u     // 32768*768 halfs (tiled, swizzle-baked)
#define WS_NEED_IMG (WS_AIMG + (size_t)M_TOT*H_DIM*2)

__device__ __forceinline__ void gload_lds16(const void* g, void* l) {
  __builtin_amdgcn_global_load_lds((const __attribute__((address_space(1))) void*)g,
                                   (__attribute__((address_space(3))) void*)l, 16, 0, 0);
}

__device__ __forceinline__ f16x8 cvt8(const float* src) {
  f32x4 x0 = *(const f32x4*)src;
  f32x4 x1 = *(const f32x4*)(src + 4);
  f16x8 h;
  h[0]=(_Float16)x0[0]; h[1]=(_Float16)x0[1]; h[2]=(_Float16)x0[2]; h[3]=(_Float16)x0[3];
  h[4]=(_Float16)x1[0]; h[5]=(_Float16)x1[1]; h[6]=(_Float16)x1[2]; h[7]=(_Float16)x1[3];
  return h;
}

__device__ __forceinline__ f16x8 cvt8v(f32x4 x0, f32x4 x1) {
  f16x8 h;
  h[0]=(_Float16)x0[0]; h[1]=(_Float16)x0[1]; h[2]=(_Float16)x0[2]; h[3]=(_Float16)x0[3];
  h[4]=(_Float16)x1[0]; h[5]=(_Float16)x1[1]; h[6]=(_Float16)x1[2]; h[7]=(_Float16)x1[3];
  return h;
}

// tanh(v) = 1 - 2/(exp2(2.885...*v)+1); limits give +-1 exactly.
__device__ __forceinline__ float fast_tanh(float v) {
  float e = __builtin_amdgcn_exp2f(v * 2.8853900817779268f);
  return 1.0f - 2.0f * __builtin_amdgcn_rcpf(e + 1.0f);
}

#define SBAR()  do { __builtin_amdgcn_sched_barrier(0); \
                     __builtin_amdgcn_s_barrier(); \
                     __builtin_amdgcn_sched_barrier(0); } while (0)

// ---------------- GEMM helpers ----------------
__device__ __forceinline__ void stage128(const _Float16* at, const _Float16* wt,
                                         _Float16* Lb, int tid) {
#pragma unroll
  for (int i = 0; i < 4; ++i) {
    int e = (tid + i*256) * 8;
    gload_lds16(at + e, Lb + e);
  }
#pragma unroll
  for (int i = 0; i < 4; ++i) {
    int e = (tid + i*256) * 8;
    gload_lds16(wt + e, Lb + 8192 + e);
  }
}

__device__ __forceinline__ void rd_frags(const _Float16* base, const int aoff[4],
                                         const int boff[4], int slot,
                                         f16x8 af[4], f16x8 bf[4]) {
#pragma unroll
  for (int mi = 0; mi < 4; ++mi) af[mi] = *(const f16x8*)(base + aoff[mi] + slot);
#pragma unroll
  for (int ni = 0; ni < 4; ++ni) bf[ni] = *(const f16x8*)(base + boff[ni] + slot);
}

__device__ __forceinline__ void mfma16(const f16x8 af[4], const f16x8 bf[4],
                                       f32x4 acc[4][4]) {
  __builtin_amdgcn_s_setprio(1);
#pragma unroll
  for (int mi = 0; mi < 4; ++mi)
#pragma unroll
    for (int ni = 0; ni < 4; ++ni)
      acc[mi][ni] = __builtin_amdgcn_mfma_f32_16x16x32_f16(af[mi], bf[ni], acc[mi][ni], 0, 0, 0);
  __builtin_amdgcn_s_setprio(0);
}

// pipelined K-step; tile tau = 12*P + j; wS monotonic (36 W tiles across 3 passes)
#define PASS_ITER(P, j) do {                                                   \
    _Float16* bufc_ = ((j) & 1) ? b1 : b0;                                     \
    _Float16* bufn_ = ((j) & 1) ? b0 : b1;                                     \
    rd_frags(bufc_, aoff, boff, slot1, af1, bf1);                              \
    mfma16(af0, bf0, acc);                                                     \
    asm volatile("s_waitcnt lgkmcnt(0)" ::: "memory");                         \
    SBAR();                                                                    \
    if ((P) < 2 || (j) < 10) {                                                 \
      const _Float16* aS = abase + (size_t)(((j) < 10) ? (j) + 2 : (j) - 10) * TILE_HALFS; \
      stage128(aS, wS, bufc_, tid);                                            \
      wS += TILE_HALFS;                                                        \
    }                                                                          \
    if ((P) == 2 && (j) == 10) { asm volatile("s_waitcnt vmcnt(0)" ::: "memory"); } \
    else                       { asm volatile("s_waitcnt vmcnt(8)" ::: "memory"); } \
    SBAR();                                                                    \
    rd_frags(bufn_, aoff, boff, slot0, af0, bf0);                              \
    mfma16(af1, bf1, acc);                                                     \
  } while (0)

#define EPI(P) do {                                                            \
    float s16_[4][4];                                                          \
    _Pragma("unroll") for (int mi = 0; mi < 4; ++mi)                           \
    _Pragma("unroll") for (int r = 0; r < 4; ++r) {                            \
      float s_ = 0.f;                                                          \
      _Pragma("unroll") for (int ni = 0; ni < 4; ++ni)                         \
        s_ = fmaf(fast_tanh(acc[mi][ni][r] + bb[P][ni]), wn[P][ni], s_);       \
      s16_[mi][r] = s_;                                                        \
    }                                                                          \
    if (wc == 0) {                                                             \
      _Pragma("unroll") for (int mi = 0; mi < 4; ++mi)                         \
      _Pragma("unroll") for (int r = 0; r < 4; ++r)                            \
        scr[(wr*64 + mi*16 + lk*4 + r)*20 + lrow] = s16_[mi][r];               \
    }                                                                          \
    asm volatile("s_waitcnt lgkmcnt(0)" ::: "memory");                         \
    SBAR();                                                                    \
    float pa_ = 0.f;                                                           \
    if (tid < 128) {                                                           \
      const f32x4* sp_ = (const f32x4*)(scr + tid*20);                         \
      f32x4 q_ = sp_[0] + sp_[1] + sp_[2] + sp_[3];                            \
      pa_ = q_[0] + q_[1] + q_[2] + q_[3];                                     \
    }                                                                          \
    asm volatile("s_waitcnt lgkmcnt(0)" ::: "memory");                         \
    SBAR();                                                                    \
    if (wc == 1) {                                                             \
      _Pragma("unroll") for (int mi = 0; mi < 4; ++mi)                         \
      _Pragma("unroll") for (int r = 0; r < 4; ++r)                            \
        scr[(wr*64 + mi*16 + lk*4 + r)*20 + lrow] = s16_[mi][r];               \
    }                                                                          \
    asm volatile("s_waitcnt lgkmcnt(0)" ::: "memory");                         \
    SBAR();                                                                    \
    if (tid < 128) {                                                           \
      const f32x4* sp_ = (const f32x4*)(scr + tid*20);                         \
      f32x4 q_ = sp_[0] + sp_[1] + sp_[2] + sp_[3];                            \
      nup[(size_t)(nb0 + (P)) * M_TOT + m0 + tid] = pa_ + q_[0]+q_[1]+q_[2]+q_[3]; \
    }                                                                          \
  } while (0)

// =================== cooperative mono-kernel ===================
// grid 512 x 256. bid -> x=bid&7, g=(bid>>3)&1, c=bid>>4; mb=c*8+x; nb0=g*3.
// (mb,g=0) and (mb,g=1) differ by 8 in bid -> same XCD -> shared A L2 locality.
__global__ __launch_bounds__(256, 2) void mono_kernel(const float* __restrict__ hs,
                                                      const float* __restrict__ Wfc,
                                                      const float* __restrict__ bfc,
                                                      const float* __restrict__ wnu,
                                                      _Float16* __restrict__ W16,
                                                      _Float16* __restrict__ Aimg,
                                                      float* __restrict__ nup,
                                                      float* __restrict__ part,
                                                      float* __restrict__ out) {
  __shared__ __align__(16) _Float16 LS[2 * BUFH];         // 64KB
  __shared__ __align__(16) float scr[128 * 20];           // 10KB (phase2) / reused phase3

  cg::grid_group grid = cg::this_grid();
  int bid = blockIdx.x;
  int x = bid & 7, g = (bid >> 3) & 1, c = bid >> 4;
  int mb = c*8 + x;               // 0..255
  int nb0 = g * 3;
  int m0 = mb * BM;
  int tid = threadIdx.x;

  // ---------------- phase 1: conversion (dedup'd) ----------------
  // block (mb,g) converts rows [m0+g*64, +64) of strip mb into image tiles.
  {
    _Float16* imgb = Aimg + (size_t)(mb * KB_CNT) * TILE_HALFS;
#pragma unroll 1
    for (int kb = 0; kb < KB_CNT; ++kb) {
      _Float16* dst = imgb + (size_t)kb * TILE_HALFS + (g*64)*BK;
#pragma unroll
      for (int i = 0; i < 2; ++i) {
        int u = tid + i*256;            // 0..511 octets of the 64-row half-tile
        int r = u >> 3, sp = u & 7;
        int sl = sp ^ (r & 7);          // g*64 == 0 mod 8
        *(f16x8*)(dst + u*8) =
            cvt8(hs + (size_t)(m0 + g*64 + r)*H_DIM + kb*BK + sl*8);
      }
    }
    // blocks 0..71 also convert one W tile each
    if (bid < NB_CNT * KB_CNT) {
      int t = bid;
      int nb = t / KB_CNT, kb = t % KB_CNT;
#pragma unroll
      for (int i = 0; i < 4; ++i) {
        int u = tid + i * 256;
        int row = u >> 3, sp = u & 7;
        int sl = sp ^ (row & 7);
        *(f16x8*)(W16 + (size_t)t*TILE_HALFS + u*8) =
            cvt8(Wfc + (size_t)(nb*BN + row)*H_DIM + kb*BK + sl*8);
      }
    }
  }
  __threadfence();
  grid.sync();

  // ---------------- phase 2: 3-pass pipelined GEMM (R6-proven) ----------------
  {
    int wv = tid >> 6, ln = tid & 63;
    int wr = wv >> 1, wc = wv & 1;
    int lrow = ln & 15, lk = ln >> 4;

    f32x4 acc[4][4] = {};
    f16x8 af0[4], bf0[4], af1[4], bf1[4];
    const _Float16* abase = Aimg + (size_t)(mb * KB_CNT) * TILE_HALFS;
    const _Float16* wbase = W16  + (size_t)(nb0 * KB_CNT) * TILE_HALFS;
    _Float16* b0 = LS;
    _Float16* b1 = LS + BUFH;

    int aoff[4], boff[4];
#pragma unroll
    for (int mi = 0; mi < 4; ++mi) aoff[mi] = (wr*64 + mi*16 + lrow) * 64;
#pragma unroll
    for (int ni = 0; ni < 4; ++ni) boff[ni] = 8192 + (wc*64 + ni*16 + lrow) * 64;
    int slot0 = ((0*4 + lk) ^ (lrow & 7)) * 8;
    int slot1 = ((1*4 + lk) ^ (lrow & 7)) * 8;

    float wn[3][4], bb[3][4];
#pragma unroll
    for (int p = 0; p < 3; ++p)
#pragma unroll
      for (int ni = 0; ni < 4; ++ni) {
        int cc = (nb0 + p)*BN + wc*64 + ni*16 + lrow;  // C/D col = lane&15 (m89-verified)
        wn[p][ni] = wnu[cc];
        bb[p][ni] = bfc[cc];
      }
    asm volatile("s_waitcnt vmcnt(0)" ::: "memory");

    stage128(abase,              wbase,              b0, tid);
    stage128(abase + TILE_HALFS, wbase + TILE_HALFS, b1, tid);
    const _Float16* wS = wbase + 2 * TILE_HALFS;    // monotonic W cursor
    asm volatile("s_waitcnt vmcnt(8)" ::: "memory");
    SBAR();
    rd_frags(b0, aoff, boff, slot0, af0, bf0);

#pragma unroll 1
    for (int j = 0; j < 12; ++j) PASS_ITER(0, j);
    EPI(0);
#pragma unroll
    for (int mi = 0; mi < 4; ++mi)
#pragma unroll
      for (int ni = 0; ni < 4; ++ni) acc[mi][ni] = f32x4{0.f, 0.f, 0.f, 0.f};

#pragma unroll 1
    for (int j = 0; j < 12; ++j) PASS_ITER(1, j);
    EPI(1);
#pragma unroll
    for (int mi = 0; mi < 4; ++mi)
#pragma unroll
      for (int ni = 0; ni < 4; ++ni) acc[mi][ni] = f32x4{0.f, 0.f, 0.f, 0.f};

#pragma unroll 1
    for (int j = 0; j < 11; ++j) PASS_ITER(2, j);
    rd_frags(b1, aoff, boff, slot1, af1, bf1);
    mfma16(af0, bf0, acc);
    mfma16(af1, bf1, acc);
    EPI(2);
  }
  __threadfence();
  grid.sync();

  // ---------------- phase 3: softmax + pooling chunk ----------------
  {
    int b = bid >> 3;
    int lc = bid & 7;
    float* al = scr;                    // reuse scratch: al[512]
    float* rr = scr + 512;              // rmax[4], rsum[4]
    float* tmp = (float*)LS;            // tmp[2][768]

    float v0 = 0.f, v1 = 0.f;
    int ms = b * L_DIM + tid;
#pragma unroll
    for (int nb = 0; nb < NB_CNT; ++nb) {
      v0 += nup[(size_t)nb * M_TOT + ms];
      v1 += nup[(size_t)nb * M_TOT + ms + 256];
    }
    int w = tid >> 6, ln = tid & 63;
    float mx = fmaxf(v0, v1);
    for (int o = 1; o < 64; o <<= 1) mx = fmaxf(mx, __shfl_xor(mx, o, 64));
    if (ln == 0) rr[w] = mx;
    __syncthreads();
    mx = fmaxf(fmaxf(rr[0], rr[1]), fmaxf(rr[2], rr[3]));
    float e0 = __expf(v0 - mx), e1 = __expf(v1 - mx);
    float sm = e0 + e1;
    for (int o = 1; o < 64; o <<= 1) sm += __shfl_xor(sm, o, 64);
    if (ln == 0) rr[4 + w] = sm;
    __syncthreads();
    float tot = rr[4] + rr[5] + rr[6] + rr[7];
    al[tid] = e0 / tot;
    al[tid + 256] = e1 / tot;
    __syncthreads();

    if (tid < 192) {
      int gg = tid % 96, rp = tid / 96;
      int kb = gg >> 3, sl = gg & 7;
      float s[8] = {};
      for (int l = rp; l < 64; l += 2) {
        int m = b * L_DIM + lc*64 + l;
        int mbb = m >> 7, row = m & 127;
        f16x8 h = *(const f16x8*)(Aimg + ((size_t)(mbb*KB_CNT + kb))*TILE_HALFS
                                  + row*64 + ((sl ^ (row & 7)) * 8));
        float a = al[lc*64 + l];
#pragma unroll
        for (int j = 0; j < 8; ++j) s[j] = fmaf(a, (float)h[j], s[j]);
      }
#pragma unroll
      for (int j = 0; j < 8; ++j) tmp[rp*H_DIM + gg*8 + j] = s[j];
    }
    __syncthreads();
    if (tid < 192) {
      float* dst = part + ((size_t)lc * B_DIM + b) * H_DIM + tid*4;
      f32x4 o;
#pragma unroll
      for (int q = 0; q < 4; ++q) o[q] = tmp[tid*4 + q] + tmp[H_DIM + tid*4 + q];
      *(f32x4*)dst = o;
    }
  }
  __threadfence();
  grid.sync();

  // ---------------- phase 4: final partial-sum (96 outputs per block) ----------------
  if (tid < 96) {
    int i = bid * 96 + tid;
    float s = 0.f;
#pragma unroll
    for (int lc = 0; lc < 8; ++lc) s += part[(size_t)lc * (B_DIM * H_DIM) + i];
    out[i] = s;
  }
}

// =================== fallback path (R10, non-cooperative) ===================
__global__ __launch_bounds__(256) void wconv_kernel(const float* __restrict__ Wfc,
                                                    _Float16* __restrict__ W16) {
  int t = blockIdx.x;
  int nb = t / KB_CNT, kb = t % KB_CNT;
#pragma unroll
  for (int i = 0; i < 4; ++i) {
    int u = threadIdx.x + i * 256;
    int row = u >> 3, sp = u & 7;
    int sl = sp ^ (row & 7);
    *(f16x8*)(W16 + (size_t)t*TILE_HALFS + u*8) =
        cvt8(Wfc + (size_t)(nb*BN + row)*H_DIM + kb*BK + sl*8);
  }
}

__global__ __launch_bounds__(256, 2) void gemm_fused_kernel(const float* __restrict__ hs,
                                                            const _Float16* __restrict__ W16,
                                                            const float* __restrict__ bfc,
                                                            const float* __restrict__ wnu,
                                                            _Float16* __restrict__ Aimg,
                                                            float* __restrict__ nup) {
  __shared__ __align__(16) _Float16 LS[2 * BUFH];
  __shared__ __align__(16) float scr[128 * 20];

  int bid = blockIdx.x;
  int mb = bid & (MB_CNT - 1);
  int nb0 = (bid >> 8) * 3;
  int m0 = mb * BM;
  int tid = threadIdx.x;
  int wv = tid >> 6, ln = tid & 63;
  int wr = wv >> 1, wc = wv & 1;
  int lrow = ln & 15, lk = ln >> 4;

  f32x4 acc[4][4] = {};
  f16x8 af0[4], bf0[4], af1[4], bf1[4];
  _Float16* imgb = Aimg + (size_t)(mb * KB_CNT) * TILE_HALFS;
  const _Float16* abase = imgb;
  const _Float16* wb0 = W16 + (size_t)(nb0 * KB_CNT) * TILE_HALFS;
  _Float16* b0 = LS;
  _Float16* b1 = LS + BUFH;

  int aoff[4], boff[4];
#pragma unroll
  for (int mi = 0; mi < 4; ++mi) aoff[mi] = (wr*64 + mi*16 + lrow) * 64;
#pragma unroll
  for (int ni = 0; ni < 4; ++ni) boff[ni] = 8192 + (wc*64 + ni*16 + lrow) * 64;
  int slot0 = ((0*4 + lk) ^ (lrow & 7)) * 8;
  int slot1 = ((1*4 + lk) ^ (lrow & 7)) * 8;

  float wn[3][4], bb[3][4];
#pragma unroll
  for (int p = 0; p < 3; ++p)
#pragma unroll
    for (int ni = 0; ni < 4; ++ni) {
      int cc = (nb0 + p)*BN + wc*64 + ni*16 + lrow;
      wn[p][ni] = wnu[cc];
      bb[p][ni] = bfc[cc];
    }
  asm volatile("s_waitcnt vmcnt(0)" ::: "memory");

  {
    int r0 = tid >> 3, sp = tid & 7;
    int sl = sp ^ (r0 & 7);
    const float* asrc = hs + (size_t)(m0 + r0) * H_DIM + sl * 8;
    f32x4 R[8]; f16x8 H[4];
#pragma unroll
    for (int i = 0; i < 4; ++i) {
      int e = (tid + i*256) * 8;
      gload_lds16(wb0 + e, b0 + 8192 + e);
    }
#pragma unroll
    for (int i = 0; i < 4; ++i) {
      const float* p = asrc + (size_t)(32*i) * H_DIM;
      R[2*i] = *(const f32x4*)p; R[2*i+1] = *(const f32x4*)(p + 4);
    }
#pragma unroll
    for (int i = 0; i < 4; ++i) H[i] = cvt8v(R[2*i], R[2*i+1]);

#pragma unroll 1
    for (int kb = 0; kb < 12; ++kb) {
      _Float16* bufc = (kb & 1) ? b1 : b0;
      _Float16* bufn = (kb & 1) ? b0 : b1;
      _Float16* idst = imgb + (size_t)kb * TILE_HALFS;
#pragma unroll
      for (int i = 0; i < 4; ++i) {
        int e = (tid + i*256) * 8;
        *(f16x8*)(bufc + e) = H[i];
        *(f16x8*)(idst + e) = H[i];
      }
      if (kb < 11) {
#pragma unroll
        for (int i = 0; i < 4; ++i) {
          int e = (tid + i*256) * 8;
          gload_lds16(wb0 + (size_t)(kb+1)*TILE_HALFS + e, bufn + 8192 + e);
        }
        const float* an = asrc + (size_t)(kb+1) * BK;
#pragma unroll
        for (int i = 0; i < 4; ++i) {
          const float* p = an + (size_t)(32*i) * H_DIM;
          R[2*i] = *(const f32x4*)p; R[2*i+1] = *(const f32x4*)(p + 4);
        }
      }
      asm volatile("s_waitcnt lgkmcnt(0)" ::: "memory");
      SBAR();
      rd_frags(bufc, aoff, boff, slot0, af0, bf0);
      mfma16(af0, bf0, acc);
      rd_frags(bufc, aoff, boff, slot1, af1, bf1);
      mfma16(af1, bf1, acc);
      if (kb < 11) {
#pragma unroll
        for (int i = 0; i < 4; ++i) H[i] = cvt8v(R[2*i], R[2*i+1]);
      }
      SBAR();
    }
  }

  const _Float16* w1b = W16 + (size_t)((nb0 + 1) * KB_CNT) * TILE_HALFS;
  stage128(abase,              w1b,              b0, tid);
  stage128(abase + TILE_HALFS, w1b + TILE_HALFS, b1, tid);
  const _Float16* wS = w1b + 2 * TILE_HALFS;
  EPI(0);
#pragma unroll
  for (int mi = 0; mi < 4; ++mi)
#pragma unroll
    for (int ni = 0; ni < 4; ++ni) acc[mi][ni] = f32x4{0.f, 0.f, 0.f, 0.f};
  asm volatile("s_waitcnt vmcnt(8)" ::: "memory");
  SBAR();
  rd_frags(b0, aoff, boff, slot0, af0, bf0);

#pragma unroll 1
  for (int j = 0; j < 12; ++j) PASS_ITER(1, j);
  EPI(1);
#pragma unroll
  for (int mi = 0; mi < 4; ++mi)
#pragma unroll
    for (int ni = 0; ni < 4; ++ni) acc[mi][ni] = f32x4{0.f, 0.f, 0.f, 0.f};

#pragma unroll 1
  for (int j = 0; j < 11; ++j) PASS_ITER(2, j);
  rd_frags(b1, aoff, boff, slot1, af1, bf1);
  mfma16(af0, bf0, acc);
  mfma16(af1, bf1, acc);
  EPI(2);
}

__global__ __launch_bounds__(256) void smpool_img_kernel(const _Float16* __restrict__ img,
                                                         const float* __restrict__ nup,
                                                         float* __restrict__ part) {
  int b = blockIdx.x >> 3;
  int lc = blockIdx.x & 7;
  int tid = threadIdx.x;
  __shared__ float al[512];
  __shared__ float rmax[4], rsum[4];
  __shared__ float tmp[2][H_DIM];

  float v0 = 0.f, v1 = 0.f;
  int ms = b * L_DIM + tid;
#pragma unroll
  for (int nb = 0; nb < NB_CNT; ++nb) {
    v0 += nup[(size_t)nb * M_TOT + ms];
    v1 += nup[(size_t)nb * M_TOT + ms + 256];
  }
  int w = tid >> 6, ln = tid & 63;
  float mx = fmaxf(v0, v1);
  for (int o = 1; o < 64; o <<= 1) mx = fmaxf(mx, __shfl_xor(mx, o, 64));
  if (ln == 0) rmax[w] = mx;
  __syncthreads();
  mx = fmaxf(fmaxf(rmax[0], rmax[1]), fmaxf(rmax[2], rmax[3]));
  float e0 = __expf(v0 - mx), e1 = __expf(v1 - mx);
  float sm = e0 + e1;
  for (int o = 1; o < 64; o <<= 1) sm += __shfl_xor(sm, o, 64);
  if (ln == 0) rsum[w] = sm;
  __syncthreads();
  float tot = rsum[0] + rsum[1] + rsum[2] + rsum[3];
  al[tid] = e0 / tot;
  al[tid + 256] = e1 / tot;
  __syncthreads();

  if (tid < 192) {
    int g = tid % 96, rp = tid / 96;
    int kb = g >> 3, sl = g & 7;
    float s[8] = {};
    for (int l = rp; l < 64; l += 2) {
      int m = b * L_DIM + lc*64 + l;
      int mb = m >> 7, row = m & 127;
      f16x8 h = *(const f16x8*)(img + ((size_t)(mb*KB_CNT + kb))*TILE_HALFS
                                + row*64 + ((sl ^ (row & 7)) * 8));
      float a = al[lc*64 + l];
#pragma unroll
      for (int j = 0; j < 8; ++j) s[j] = fmaf(a, (float)h[j], s[j]);
    }
#pragma unroll
    for (int j = 0; j < 8; ++j) tmp[rp][g*8 + j] = s[j];
  }
  __syncthreads();
  if (tid < 192) {
    float* dst = part + ((size_t)lc * B_DIM + b) * H_DIM + tid*4;
    f32x4 o;
#pragma unroll
    for (int q = 0; q < 4; ++q) o[q] = tmp[0][tid*4 + q] + tmp[1][tid*4 + q];
    *(f32x4*)dst = o;
  }
}

__global__ __launch_bounds__(256) void pool2_kernel(const float* __restrict__ part,
                                                    float* __restrict__ out) {
  int i = blockIdx.x * 256 + threadIdx.x;
  float s = 0.f;
  for (int lc = 0; lc < 8; ++lc) s += part[(size_t)lc * (B_DIM * H_DIM) + i];
  out[i] = s;
}

extern "C" void kernel_launch(void* const* d_in, const int* in_sizes, int n_in,
                              void* d_out, int out_size, void* d_ws, size_t ws_size,
                              hipStream_t stream) {
  const float* hs  = (const float*)d_in[0];
  const float* Wfc = (const float*)d_in[1];
  const float* bfc = (const float*)d_in[2];
  const float* wnu = (const float*)d_in[3];
  float* out = (float*)d_out;
  char* ws = (char*)d_ws;
  _Float16* W16 = (_Float16*)(ws + WS_W16);
  float* nup    = (float*)(ws + WS_NUP);
  float* part   = (float*)(ws + WS_POOL);
  _Float16* Aimg = (_Float16*)(ws + WS_AIMG);

  bool img = (ws_size >= WS_NEED_IMG);

  int coopAttr = 0;
  (void)hipDeviceGetAttribute(&coopAttr, hipDeviceAttributeCooperativeLaunch, 0);

  if (img && coopAttr) {
    void* args[] = {(void*)&hs, (void*)&Wfc, (void*)&bfc, (void*)&wnu,
                    (void*)&W16, (void*)&Aimg, (void*)&nup, (void*)&part, (void*)&out};
    hipError_t err = hipLaunchCooperativeKernel((const void*)mono_kernel,
                                                dim3(512), dim3(256), args, 0, stream);
    if (err == hipSuccess) return;
  }

  // fallback: proven R10 path
  wconv_kernel<<<NB_CNT * KB_CNT, 256, 0, stream>>>(Wfc, W16);
  if (img) {
    gemm_fused_kernel<<<MB_CNT * 2, 256, 0, stream>>>(hs, W16, bfc, wnu, Aimg, nup);
    smpool_img_kernel<<<B_DIM * 8, 256, 0, stream>>>(Aimg, nup, part);
    pool2_kernel<<<192, 256, 0, stream>>>(part, out);
  } else {
    // minimal correct path without image: reuse fused kernel requires image; use it anyway
    gemm_fused_kernel<<<MB_CNT * 2, 256, 0, stream>>>(hs, W16, bfc, wnu, Aimg, nup);
    smpool_img_kernel<<<B_DIM * 8, 256, 0, stream>>>(Aimg, nup, part);
    pool2_kernel<<<192, 256, 0, stream>>>(part, out);
  }
}

// Round 12
// 90.073 us; speedup vs baseline: 4.3741x; 4.3741x over previous
//
#include <hip/hip_runtime.h>

#define H_DIM 768
#define B_DIM 64
#define L_DIM 512
#define M_TOT (B_DIM*L_DIM)   // 32768
#define BM 128
#define BN 128
#define BK 64
#define NB_CNT (H_DIM/BN)     // 6
#define KB_CNT (H_DIM/BK)     // 12
#define MB_CNT (M_TOT/BM)     // 256
#define TILE_HALFS (BM*BK)    // 8192 halfs = 16KB
#define BUFH 16384            // halfs per LDS buffer (A 8192 + B 8192 = 32KB)

typedef _Float16 f16x8 __attribute__((ext_vector_type(8)));
typedef float f32x4 __attribute__((ext_vector_type(4)));

// ws byte offsets
#define WS_W16   0u           // 768*768 halfs (tiled, swizzle-baked)
#define WS_NUP   1179648u     // 6*32768 f32
#define WS_ALPHA 1966080u     // 32768 f32
#define WS_POOL  2097152u     // 8*64*768 f32
#define WS_AIMG  3670016u     // 32768*768 halfs (tiled; written by gemm pass 0)
#define WS_NEED_IMG (WS_AIMG + (size_t)M_TOT*H_DIM*2)

__device__ __forceinline__ void gload_lds16(const void* g, void* l) {
  __builtin_amdgcn_global_load_lds((const __attribute__((address_space(1))) void*)g,
                                   (__attribute__((address_space(3))) void*)l, 16, 0, 0);
}

__device__ __forceinline__ f16x8 cvt8(const float* src) {
  f32x4 x0 = *(const f32x4*)src;
  f32x4 x1 = *(const f32x4*)(src + 4);
  f16x8 h;
  h[0]=(_Float16)x0[0]; h[1]=(_Float16)x0[1]; h[2]=(_Float16)x0[2]; h[3]=(_Float16)x0[3];
  h[4]=(_Float16)x1[0]; h[5]=(_Float16)x1[1]; h[6]=(_Float16)x1[2]; h[7]=(_Float16)x1[3];
  return h;
}

__device__ __forceinline__ f16x8 cvt8v(f32x4 x0, f32x4 x1) {
  f16x8 h;
  h[0]=(_Float16)x0[0]; h[1]=(_Float16)x0[1]; h[2]=(_Float16)x0[2]; h[3]=(_Float16)x0[3];
  h[4]=(_Float16)x1[0]; h[5]=(_Float16)x1[1]; h[6]=(_Float16)x1[2]; h[7]=(_Float16)x1[3];
  return h;
}

// tanh(v) = 1 - 2/(exp2(2.885...*v)+1); limits give +-1 exactly.
__device__ __forceinline__ float fast_tanh(float v) {
  float e = __builtin_amdgcn_exp2f(v * 2.8853900817779268f);
  return 1.0f - 2.0f * __builtin_amdgcn_rcpf(e + 1.0f);
}

#define SBAR()  do { __builtin_amdgcn_sched_barrier(0); \
                     __builtin_amdgcn_s_barrier(); \
                     __builtin_amdgcn_sched_barrier(0); } while (0)

// ---------------- kernel 1: W_fc fp32 -> fp16 tiled image (72 blocks only) ----------
__global__ __launch_bounds__(256) void wconv_kernel(const float* __restrict__ Wfc,
                                                    _Float16* __restrict__ W16) {
  int t = blockIdx.x;             // 0..71
  int nb = t / KB_CNT, kb = t % KB_CNT;
#pragma unroll
  for (int i = 0; i < 4; ++i) {
    int u = threadIdx.x + i * 256;
    int row = u >> 3, sp = u & 7;
    int sl = sp ^ (row & 7);
    *(f16x8*)(W16 + (size_t)t*TILE_HALFS + u*8) =
        cvt8(Wfc + (size_t)(nb*BN + row)*H_DIM + kb*BK + sl*8);
  }
}

// ---------------- GEMM helpers ----------------
__device__ __forceinline__ void stage128(const _Float16* at, const _Float16* wt,
                                         _Float16* Lb, int tid) {
#pragma unroll
  for (int i = 0; i < 4; ++i) {
    int e = (tid + i*256) * 8;
    gload_lds16(at + e, Lb + e);
  }
#pragma unroll
  for (int i = 0; i < 4; ++i) {
    int e = (tid + i*256) * 8;
    gload_lds16(wt + e, Lb + 8192 + e);
  }
}

__device__ __forceinline__ void rd_frags(const _Float16* base, const int aoff[4],
                                         const int boff[4], int slot,
                                         f16x8 af[4], f16x8 bf[4]) {
#pragma unroll
  for (int mi = 0; mi < 4; ++mi) af[mi] = *(const f16x8*)(base + aoff[mi] + slot);
#pragma unroll
  for (int ni = 0; ni < 4; ++ni) bf[ni] = *(const f16x8*)(base + boff[ni] + slot);
}

__device__ __forceinline__ void mfma16(const f16x8 af[4], const f16x8 bf[4],
                                       f32x4 acc[4][4]) {
  __builtin_amdgcn_s_setprio(1);
#pragma unroll
  for (int mi = 0; mi < 4; ++mi)
#pragma unroll
    for (int ni = 0; ni < 4; ++ni)
      acc[mi][ni] = __builtin_amdgcn_mfma_f32_16x16x32_f16(af[mi], bf[ni], acc[mi][ni], 0, 0, 0);
  __builtin_amdgcn_s_setprio(0);
}

// One pipelined iteration (passes 1,2). P=1: stage always (j<10 own tile j+2;
// j=10,11 next pass tiles 0,1). P=2: stage only j<10; j=10 drains.
#define PASS_ITER(P, j) do {                                                   \
    _Float16* bufc_ = ((j) & 1) ? b1 : b0;                                     \
    _Float16* bufn_ = ((j) & 1) ? b0 : b1;                                     \
    rd_frags(bufc_, aoff, boff, slot1, af1, bf1);                              \
    mfma16(af0, bf0, acc);                                                     \
    asm volatile("s_waitcnt lgkmcnt(0)" ::: "memory");                         \
    SBAR();                                                                    \
    if ((P) < 2 || (j) < 10) {                                                 \
      const _Float16* aS = abase + (size_t)(((j) < 10) ? (j) + 2 : (j) - 10) * TILE_HALFS; \
      stage128(aS, wS, bufc_, tid);                                            \
      wS += TILE_HALFS;                                                        \
    }                                                                          \
    if ((P) == 2 && (j) == 10) { asm volatile("s_waitcnt vmcnt(0)" ::: "memory"); } \
    else                       { asm volatile("s_waitcnt vmcnt(8)" ::: "memory"); } \
    SBAR();                                                                    \
    rd_frags(bufn_, aoff, boff, slot0, af0, bf0);                              \
    mfma16(af1, bf1, acc);                                                     \
  } while (0)

// Per-pass epilogue: tanh + wnu-dot + LDS-transpose reduction + store.
#define EPI(P) do {                                                            \
    float s16_[4][4];                                                          \
    _Pragma("unroll") for (int mi = 0; mi < 4; ++mi)                           \
    _Pragma("unroll") for (int r = 0; r < 4; ++r) {                            \
      float s_ = 0.f;                                                          \
      _Pragma("unroll") for (int ni = 0; ni < 4; ++ni)                         \
        s_ = fmaf(fast_tanh(acc[mi][ni][r] + bb[P][ni]), wn[P][ni], s_);       \
      s16_[mi][r] = s_;                                                        \
    }                                                                          \
    if (wc == 0) {                                                             \
      _Pragma("unroll") for (int mi = 0; mi < 4; ++mi)                         \
      _Pragma("unroll") for (int r = 0; r < 4; ++r)                            \
        scr[(wr*64 + mi*16 + lk*4 + r)*20 + lrow] = s16_[mi][r];               \
    }                                                                          \
    asm volatile("s_waitcnt lgkmcnt(0)" ::: "memory");                         \
    SBAR();                                                                    \
    float pa_ = 0.f;                                                           \
    if (tid < 128) {                                                           \
      const f32x4* sp_ = (const f32x4*)(scr + tid*20);                         \
      f32x4 q_ = sp_[0] + sp_[1] + sp_[2] + sp_[3];                            \
      pa_ = q_[0] + q_[1] + q_[2] + q_[3];                                     \
    }                                                                          \
    asm volatile("s_waitcnt lgkmcnt(0)" ::: "memory");                         \
    SBAR();                                                                    \
    if (wc == 1) {                                                             \
      _Pragma("unroll") for (int mi = 0; mi < 4; ++mi)                         \
      _Pragma("unroll") for (int r = 0; r < 4; ++r)                            \
        scr[(wr*64 + mi*16 + lk*4 + r)*20 + lrow] = s16_[mi][r];               \
    }                                                                          \
    asm volatile("s_waitcnt lgkmcnt(0)" ::: "memory");                         \
    SBAR();                                                                    \
    if (tid < 128) {                                                           \
      const f32x4* sp_ = (const f32x4*)(scr + tid*20);                         \
      f32x4 q_ = sp_[0] + sp_[1] + sp_[2] + sp_[3];                            \
      nup[(size_t)(nb0 + (P)) * M_TOT + m0 + tid] = pa_ + q_[0]+q_[1]+q_[2]+q_[3]; \
    }                                                                          \
  } while (0)

// ---------------- kernel 2: fused conv+GEMM, 3 nb passes per block (R8, proven) ----
__global__ __launch_bounds__(256, 2) void gemm_fused_kernel(const float* __restrict__ hs,
                                                            const _Float16* __restrict__ W16,
                                                            const float* __restrict__ bfc,
                                                            const float* __restrict__ wnu,
                                                            _Float16* __restrict__ Aimg,
                                                            float* __restrict__ nup) {
  __shared__ __align__(16) _Float16 LS[2 * BUFH];         // 64KB double buffer
  __shared__ __align__(16) float scr[128 * 20];           // 10KB reduce scratch

  int bid = blockIdx.x;
  int mb = bid & (MB_CNT - 1);    // 0..255
  int nb0 = (bid >> 8) * 3;       // 0 or 3
  int m0 = mb * BM;
  int tid = threadIdx.x;
  int wv = tid >> 6, ln = tid & 63;
  int wr = wv >> 1, wc = wv & 1;  // 2x2 wave grid, 64x64 output each
  int lrow = ln & 15, lk = ln >> 4;

  f32x4 acc[4][4] = {};
  f16x8 af0[4], bf0[4], af1[4], bf1[4];
  _Float16* imgb = Aimg + (size_t)(mb * KB_CNT) * TILE_HALFS;
  const _Float16* abase = imgb;
  const _Float16* wb0 = W16 + (size_t)(nb0 * KB_CNT) * TILE_HALFS;
  _Float16* b0 = LS;
  _Float16* b1 = LS + BUFH;

  int aoff[4], boff[4];
#pragma unroll
  for (int mi = 0; mi < 4; ++mi) aoff[mi] = (wr*64 + mi*16 + lrow) * 64;
#pragma unroll
  for (int ni = 0; ni < 4; ++ni) boff[ni] = 8192 + (wc*64 + ni*16 + lrow) * 64;
  int slot0 = ((0*4 + lk) ^ (lrow & 7)) * 8;
  int slot1 = ((1*4 + lk) ^ (lrow & 7)) * 8;

  float wn[3][4], bb[3][4];
#pragma unroll
  for (int p = 0; p < 3; ++p)
#pragma unroll
    for (int ni = 0; ni < 4; ++ni) {
      int c = (nb0 + p)*BN + wc*64 + ni*16 + lrow;  // C/D col = lane&15 (m89-verified)
      wn[p][ni] = wnu[c];
      bb[p][ni] = bfc[c];
    }
  asm volatile("s_waitcnt vmcnt(0)" ::: "memory");

  // ================= pass 0: fused convert+GEMM =================
  {
    int r0 = tid >> 3, sp = tid & 7;
    int sl = sp ^ (r0 & 7);                          // same sl for all 4 sub-rows (32 ≡ 0 mod 8)
    const float* asrc = hs + (size_t)(m0 + r0) * H_DIM + sl * 8;
    f32x4 R[8]; f16x8 H[4];
    // prologue: W(0) gloads + A(0) fp32 loads
#pragma unroll
    for (int i = 0; i < 4; ++i) {
      int e = (tid + i*256) * 8;
      gload_lds16(wb0 + e, b0 + 8192 + e);
    }
#pragma unroll
    for (int i = 0; i < 4; ++i) {
      const float* p = asrc + (size_t)(32*i) * H_DIM;
      R[2*i] = *(const f32x4*)p; R[2*i+1] = *(const f32x4*)(p + 4);
    }
#pragma unroll
    for (int i = 0; i < 4; ++i) H[i] = cvt8v(R[2*i], R[2*i+1]);  // data-dep waits loads (W older -> also done)

#pragma unroll 1
    for (int kb = 0; kb < 12; ++kb) {
      _Float16* bufc = (kb & 1) ? b1 : b0;
      _Float16* bufn = (kb & 1) ? b0 : b1;
      _Float16* idst = imgb + (size_t)kb * TILE_HALFS;
      // commit current tile: LDS + image
#pragma unroll
      for (int i = 0; i < 4; ++i) {
        int e = (tid + i*256) * 8;
        *(f16x8*)(bufc + e) = H[i];                  // ds_write_b128
        *(f16x8*)(idst + e) = H[i];                  // global_store (image)
      }
      // issue next tile's W gloads + A fp32 loads (latency hides under MFMA below)
      if (kb < 11) {
#pragma unroll
        for (int i = 0; i < 4; ++i) {
          int e = (tid + i*256) * 8;
          gload_lds16(wb0 + (size_t)(kb+1)*TILE_HALFS + e, bufn + 8192 + e);
        }
        const float* an = asrc + (size_t)(kb+1) * BK;
#pragma unroll
        for (int i = 0; i < 4; ++i) {
          const float* p = an + (size_t)(32*i) * H_DIM;
          R[2*i] = *(const f32x4*)p; R[2*i+1] = *(const f32x4*)(p + 4);
        }
      }
      asm volatile("s_waitcnt lgkmcnt(0)" ::: "memory");  // ds_writes committed
      SBAR();                                             // W(kb) landed (in-order: older than consumed A(kb))
      rd_frags(bufc, aoff, boff, slot0, af0, bf0);
      mfma16(af0, bf0, acc);
      rd_frags(bufc, aoff, boff, slot1, af1, bf1);
      mfma16(af1, bf1, acc);
      if (kb < 11) {
#pragma unroll
        for (int i = 0; i < 4; ++i) H[i] = cvt8v(R[2*i], R[2*i+1]);  // waits A(kb+1)
      }
      SBAR();                                             // protect bufn.B from next iter's gloads
    }
  }

  // ================= transition: prologue of pass 1 under EPI(0) =================
  const _Float16* w1b = W16 + (size_t)((nb0 + 1) * KB_CNT) * TILE_HALFS;
  stage128(abase,              w1b,              b0, tid);
  stage128(abase + TILE_HALFS, w1b + TILE_HALFS, b1, tid);
  const _Float16* wS = w1b + 2 * TILE_HALFS;      // monotonic W stage cursor
  EPI(0);
#pragma unroll
  for (int mi = 0; mi < 4; ++mi)
#pragma unroll
    for (int ni = 0; ni < 4; ++ni) acc[mi][ni] = f32x4{0.f, 0.f, 0.f, 0.f};
  asm volatile("s_waitcnt vmcnt(8)" ::: "memory");  // pass-0 stores + t0 landed (t1's 8 in flight)
  SBAR();
  rd_frags(b0, aoff, boff, slot0, af0, bf0);        // pass-1 t0 kk0

  // ---- pass 1 ----
#pragma unroll 1
  for (int j = 0; j < 12; ++j) PASS_ITER(1, j);
  EPI(1);
#pragma unroll
  for (int mi = 0; mi < 4; ++mi)
#pragma unroll
    for (int ni = 0; ni < 4; ++ni) acc[mi][ni] = f32x4{0.f, 0.f, 0.f, 0.f};

  // ---- pass 2 (last tile peeled) ----
#pragma unroll 1
  for (int j = 0; j < 11; ++j) PASS_ITER(2, j);
  rd_frags(b1, aoff, boff, slot1, af1, bf1);        // t11 kk1
  mfma16(af0, bf0, acc);                            // t11 kk0
  mfma16(af1, bf1, acc);                            // t11 kk1
  EPI(2);
}

// ---------------- kernel 3: softmax over L per batch ----------------
__global__ __launch_bounds__(512) void softmax_kernel(const float* __restrict__ nup,
                                                      float* __restrict__ alphas) {
  int b = blockIdx.x;
  int l = threadIdx.x;
  int m = b * L_DIM + l;
  float v = 0.f;
  for (int nb = 0; nb < NB_CNT; ++nb) v += nup[(size_t)nb * M_TOT + m];
  __shared__ float smax[8], ssum[8];
  int w = l >> 6, ln = l & 63;
  float mx = v;
  for (int o = 1; o < 64; o <<= 1) mx = fmaxf(mx, __shfl_xor(mx, o, 64));
  if (ln == 0) smax[w] = mx;
  __syncthreads();
  mx = smax[0];
  for (int i = 1; i < 8; ++i) mx = fmaxf(mx, smax[i]);
  float e = __expf(v - mx);
  float sm = e;
  for (int o = 1; o < 64; o <<= 1) sm += __shfl_xor(sm, o, 64);
  if (ln == 0) ssum[w] = sm;
  __syncthreads();
  float tot = 0.f;
  for (int i = 0; i < 8; ++i) tot += ssum[i];
  alphas[m] = e / tot;
}

// ---------------- pooling from fp16 A-image ----------------
__global__ __launch_bounds__(192) void pool1_img_kernel(const _Float16* __restrict__ img,
                                                        const float* __restrict__ alphas,
                                                        float* __restrict__ part) {
  int b = blockIdx.x >> 3;
  int lc = blockIdx.x & 7;
  int tid = threadIdx.x;
  int g = tid % 96, rp = tid / 96;
  int kb = g >> 3, sl = g & 7;
  __shared__ float al[64];
  __shared__ float tmp[2][H_DIM];
  if (tid < 64) al[tid] = alphas[b * L_DIM + lc*64 + tid];
  __syncthreads();
  float s[8] = {};
  for (int l = rp; l < 64; l += 2) {
    int m = b * L_DIM + lc*64 + l;
    int mb = m >> 7, row = m & 127;
    const f16x8* src = (const f16x8*)(img + ((size_t)(mb*KB_CNT + kb))*TILE_HALFS
                                      + row*64 + ((sl ^ (row & 7)) * 8));
    f16x8 h = *src;
    float a = al[l];
#pragma unroll
    for (int j = 0; j < 8; ++j) s[j] = fmaf(a, (float)h[j], s[j]);
  }
#pragma unroll
  for (int j = 0; j < 8; ++j) tmp[rp][g*8 + j] = s[j];
  __syncthreads();
  float* dst = part + ((size_t)lc * B_DIM + b) * H_DIM + tid*4;
  f32x4 o;
#pragma unroll
  for (int q = 0; q < 4; ++q) o[q] = tmp[0][tid*4 + q] + tmp[1][tid*4 + q];
  *(f32x4*)dst = o;
}

__global__ __launch_bounds__(256) void pool2_kernel(const float* __restrict__ part,
                                                    float* __restrict__ out) {
  int i = blockIdx.x * 256 + threadIdx.x;
  float s = 0.f;
  for (int lc = 0; lc < 8; ++lc) s += part[(size_t)lc * (B_DIM * H_DIM) + i];
  out[i] = s;
}

extern "C" void kernel_launch(void* const* d_in, const int* in_sizes, int n_in,
                              void* d_out, int out_size, void* d_ws, size_t ws_size,
                              hipStream_t stream) {
  const float* hs  = (const float*)d_in[0];
  const float* Wfc = (const float*)d_in[1];
  const float* bfc = (const float*)d_in[2];
  const float* wnu = (const float*)d_in[3];
  float* out = (float*)d_out;
  char* ws = (char*)d_ws;
  _Float16* W16 = (_Float16*)(ws + WS_W16);
  float* nup    = (float*)(ws + WS_NUP);
  float* alphas = (float*)(ws + WS_ALPHA);
  float* part   = (float*)(ws + WS_POOL);
  _Float16* Aimg = (_Float16*)(ws + WS_AIMG);

  wconv_kernel<<<NB_CNT * KB_CNT, 256, 0, stream>>>(Wfc, W16);
  gemm_fused_kernel<<<MB_CNT * 2, 256, 0, stream>>>(hs, W16, bfc, wnu, Aimg, nup);
  softmax_kernel<<<B_DIM, 512, 0, stream>>>(nup, alphas);
  pool1_img_kernel<<<B_DIM * 8, 192, 0, stream>>>(Aimg, alphas, part);
  pool2_kernel<<<192, 256, 0, stream>>>(part, out);
}

// Round 13
// 84.536 us; speedup vs baseline: 4.6606x; 1.0655x over previous
//
#include <hip/hip_runtime.h>

#define H_DIM 768
#define B_DIM 64
#define L_DIM 512
#define M_TOT (B_DIM*L_DIM)   // 32768
#define BM 128
#define BN 128
#define BK 64
#define NB_CNT (H_DIM/BN)     // 6
#define KB_CNT (H_DIM/BK)     // 12
#define MB_CNT (M_TOT/BM)     // 256
#define TILE_HALFS (BM*BK)    // 8192 halfs = 16KB
#define BUFH 16384            // halfs per LDS buffer (A 8192 + B 8192 = 32KB)

typedef _Float16 f16x8 __attribute__((ext_vector_type(8)));
typedef float f32x4 __attribute__((ext_vector_type(4)));

// ws byte offsets
#define WS_W16   0u           // 768*768 halfs (tiled, swizzle-baked)
#define WS_NUP   1179648u     // 6*32768 f32
#define WS_ALPHA 1966080u     // 32768 f32
#define WS_POOL  2097152u     // 8*64*768 f32
#define WS_AIMG  3670016u     // 32768*768 halfs (tiled; written by gemm pass 0)
#define WS_NEED_IMG (WS_AIMG + (size_t)M_TOT*H_DIM*2)

__device__ __forceinline__ void gload_lds16(const void* g, void* l) {
  __builtin_amdgcn_global_load_lds((const __attribute__((address_space(1))) void*)g,
                                   (__attribute__((address_space(3))) void*)l, 16, 0, 0);
}

__device__ __forceinline__ f16x8 cvt8(const float* src) {
  f32x4 x0 = *(const f32x4*)src;
  f32x4 x1 = *(const f32x4*)(src + 4);
  f16x8 h;
  h[0]=(_Float16)x0[0]; h[1]=(_Float16)x0[1]; h[2]=(_Float16)x0[2]; h[3]=(_Float16)x0[3];
  h[4]=(_Float16)x1[0]; h[5]=(_Float16)x1[1]; h[6]=(_Float16)x1[2]; h[7]=(_Float16)x1[3];
  return h;
}

__device__ __forceinline__ f16x8 cvt8v(f32x4 x0, f32x4 x1) {
  f16x8 h;
  h[0]=(_Float16)x0[0]; h[1]=(_Float16)x0[1]; h[2]=(_Float16)x0[2]; h[3]=(_Float16)x0[3];
  h[4]=(_Float16)x1[0]; h[5]=(_Float16)x1[1]; h[6]=(_Float16)x1[2]; h[7]=(_Float16)x1[3];
  return h;
}

// tanh(v) = 1 - 2/(exp2(2.885...*v)+1); limits give +-1 exactly.
__device__ __forceinline__ float fast_tanh(float v) {
  float e = __builtin_amdgcn_exp2f(v * 2.8853900817779268f);
  return 1.0f - 2.0f * __builtin_amdgcn_rcpf(e + 1.0f);
}

#define SBAR()  do { __builtin_amdgcn_sched_barrier(0); \
                     __builtin_amdgcn_s_barrier(); \
                     __builtin_amdgcn_sched_barrier(0); } while (0)

// ---------------- kernel 1: W_fc fp32 -> fp16 tiled image (72 blocks only) ----------
__global__ __launch_bounds__(256) void wconv_kernel(const float* __restrict__ Wfc,
                                                    _Float16* __restrict__ W16) {
  int t = blockIdx.x;             // 0..71
  int nb = t / KB_CNT, kb = t % KB_CNT;
#pragma unroll
  for (int i = 0; i < 4; ++i) {
    int u = threadIdx.x + i * 256;
    int row = u >> 3, sp = u & 7;
    int sl = sp ^ (row & 7);
    *(f16x8*)(W16 + (size_t)t*TILE_HALFS + u*8) =
        cvt8(Wfc + (size_t)(nb*BN + row)*H_DIM + kb*BK + sl*8);
  }
}

// ---------------- GEMM helpers ----------------
__device__ __forceinline__ void stage128(const _Float16* at, const _Float16* wt,
                                         _Float16* Lb, int tid) {
#pragma unroll
  for (int i = 0; i < 4; ++i) {
    int e = (tid + i*256) * 8;
    gload_lds16(at + e, Lb + e);
  }
#pragma unroll
  for (int i = 0; i < 4; ++i) {
    int e = (tid + i*256) * 8;
    gload_lds16(wt + e, Lb + 8192 + e);
  }
}

__device__ __forceinline__ void rd_frags(const _Float16* base, const int aoff[4],
                                         const int boff[4], int slot,
                                         f16x8 af[4], f16x8 bf[4]) {
#pragma unroll
  for (int mi = 0; mi < 4; ++mi) af[mi] = *(const f16x8*)(base + aoff[mi] + slot);
#pragma unroll
  for (int ni = 0; ni < 4; ++ni) bf[ni] = *(const f16x8*)(base + boff[ni] + slot);
}

__device__ __forceinline__ void mfma16(const f16x8 af[4], const f16x8 bf[4],
                                       f32x4 acc[4][4]) {
  __builtin_amdgcn_s_setprio(1);
#pragma unroll
  for (int mi = 0; mi < 4; ++mi)
#pragma unroll
    for (int ni = 0; ni < 4; ++ni)
      acc[mi][ni] = __builtin_amdgcn_mfma_f32_16x16x32_f16(af[mi], bf[ni], acc[mi][ni], 0, 0, 0);
  __builtin_amdgcn_s_setprio(0);
}

// One pipelined iteration (passes 1,2). P=1: stage always (j<10 own tile j+2;
// j=10,11 next pass tiles 0,1). P=2: stage only j<10; j=10 drains.
#define PASS_ITER(P, j) do {                                                   \
    _Float16* bufc_ = ((j) & 1) ? b1 : b0;                                     \
    _Float16* bufn_ = ((j) & 1) ? b0 : b1;                                     \
    rd_frags(bufc_, aoff, boff, slot1, af1, bf1);                              \
    mfma16(af0, bf0, acc);                                                     \
    asm volatile("s_waitcnt lgkmcnt(0)" ::: "memory");                         \
    SBAR();                                                                    \
    if ((P) < 2 || (j) < 10) {                                                 \
      const _Float16* aS = abase + (size_t)(((j) < 10) ? (j) + 2 : (j) - 10) * TILE_HALFS; \
      stage128(aS, wS, bufc_, tid);                                            \
      wS += TILE_HALFS;                                                        \
    }                                                                          \
    if ((P) == 2 && (j) == 10) { asm volatile("s_waitcnt vmcnt(0)" ::: "memory"); } \
    else                       { asm volatile("s_waitcnt vmcnt(8)" ::: "memory"); } \
    SBAR();                                                                    \
    rd_frags(bufn_, aoff, boff, slot0, af0, bf0);                              \
    mfma16(af1, bf1, acc);                                                     \
  } while (0)

// Per-pass epilogue: tanh + wnu-dot + LDS-transpose reduction + store.
#define EPI(P) do {                                                            \
    float s16_[4][4];                                                          \
    _Pragma("unroll") for (int mi = 0; mi < 4; ++mi)                           \
    _Pragma("unroll") for (int r = 0; r < 4; ++r) {                            \
      float s_ = 0.f;                                                          \
      _Pragma("unroll") for (int ni = 0; ni < 4; ++ni)                         \
        s_ = fmaf(fast_tanh(acc[mi][ni][r] + bb[P][ni]), wn[P][ni], s_);       \
      s16_[mi][r] = s_;                                                        \
    }                                                                          \
    if (wc == 0) {                                                             \
      _Pragma("unroll") for (int mi = 0; mi < 4; ++mi)                         \
      _Pragma("unroll") for (int r = 0; r < 4; ++r)                            \
        scr[(wr*64 + mi*16 + lk*4 + r)*20 + lrow] = s16_[mi][r];               \
    }                                                                          \
    asm volatile("s_waitcnt lgkmcnt(0)" ::: "memory");                         \
    SBAR();                                                                    \
    float pa_ = 0.f;                                                           \
    if (tid < 128) {                                                           \
      const f32x4* sp_ = (const f32x4*)(scr + tid*20);                         \
      f32x4 q_ = sp_[0] + sp_[1] + sp_[2] + sp_[3];                            \
      pa_ = q_[0] + q_[1] + q_[2] + q_[3];                                     \
    }                                                                          \
    asm volatile("s_waitcnt lgkmcnt(0)" ::: "memory");                         \
    SBAR();                                                                    \
    if (wc == 1) {                                                             \
      _Pragma("unroll") for (int mi = 0; mi < 4; ++mi)                         \
      _Pragma("unroll") for (int r = 0; r < 4; ++r)                            \
        scr[(wr*64 + mi*16 + lk*4 + r)*20 + lrow] = s16_[mi][r];               \
    }                                                                          \
    asm volatile("s_waitcnt lgkmcnt(0)" ::: "memory");                         \
    SBAR();                                                                    \
    if (tid < 128) {                                                           \
      const f32x4* sp_ = (const f32x4*)(scr + tid*20);                         \
      f32x4 q_ = sp_[0] + sp_[1] + sp_[2] + sp_[3];                            \
      nup[(size_t)(nb0 + (P)) * M_TOT + m0 + tid] = pa_ + q_[0]+q_[1]+q_[2]+q_[3]; \
    }                                                                          \
  } while (0)

// ---------------- kernel 2: fused conv+GEMM, 3 nb passes per block (R8, proven) ----
__global__ __launch_bounds__(256, 2) void gemm_fused_kernel(const float* __restrict__ hs,
                                                            const _Float16* __restrict__ W16,
                                                            const float* __restrict__ bfc,
                                                            const float* __restrict__ wnu,
                                                            _Float16* __restrict__ Aimg,
                                                            float* __restrict__ nup) {
  __shared__ __align__(16) _Float16 LS[2 * BUFH];         // 64KB double buffer
  __shared__ __align__(16) float scr[128 * 20];           // 10KB reduce scratch

  int bid = blockIdx.x;
  int mb = bid & (MB_CNT - 1);    // 0..255
  int nb0 = (bid >> 8) * 3;       // 0 or 3
  int m0 = mb * BM;
  int tid = threadIdx.x;
  int wv = tid >> 6, ln = tid & 63;
  int wr = wv >> 1, wc = wv & 1;  // 2x2 wave grid, 64x64 output each
  int lrow = ln & 15, lk = ln >> 4;

  f32x4 acc[4][4] = {};
  f16x8 af0[4], bf0[4], af1[4], bf1[4];
  _Float16* imgb = Aimg + (size_t)(mb * KB_CNT) * TILE_HALFS;
  const _Float16* abase = imgb;
  const _Float16* wb0 = W16 + (size_t)(nb0 * KB_CNT) * TILE_HALFS;
  _Float16* b0 = LS;
  _Float16* b1 = LS + BUFH;

  int aoff[4], boff[4];
#pragma unroll
  for (int mi = 0; mi < 4; ++mi) aoff[mi] = (wr*64 + mi*16 + lrow) * 64;
#pragma unroll
  for (int ni = 0; ni < 4; ++ni) boff[ni] = 8192 + (wc*64 + ni*16 + lrow) * 64;
  int slot0 = ((0*4 + lk) ^ (lrow & 7)) * 8;
  int slot1 = ((1*4 + lk) ^ (lrow & 7)) * 8;

  float wn[3][4], bb[3][4];
#pragma unroll
  for (int p = 0; p < 3; ++p)
#pragma unroll
    for (int ni = 0; ni < 4; ++ni) {
      int c = (nb0 + p)*BN + wc*64 + ni*16 + lrow;  // C/D col = lane&15 (m89-verified)
      wn[p][ni] = wnu[c];
      bb[p][ni] = bfc[c];
    }
  asm volatile("s_waitcnt vmcnt(0)" ::: "memory");

  // ================= pass 0: fused convert+GEMM =================
  {
    int r0 = tid >> 3, sp = tid & 7;
    int sl = sp ^ (r0 & 7);                          // same sl for all 4 sub-rows (32 ≡ 0 mod 8)
    const float* asrc = hs + (size_t)(m0 + r0) * H_DIM + sl * 8;
    f32x4 R[8]; f16x8 H[4];
    // prologue: W(0) gloads + A(0) fp32 loads
#pragma unroll
    for (int i = 0; i < 4; ++i) {
      int e = (tid + i*256) * 8;
      gload_lds16(wb0 + e, b0 + 8192 + e);
    }
#pragma unroll
    for (int i = 0; i < 4; ++i) {
      const float* p = asrc + (size_t)(32*i) * H_DIM;
      R[2*i] = *(const f32x4*)p; R[2*i+1] = *(const f32x4*)(p + 4);
    }
#pragma unroll
    for (int i = 0; i < 4; ++i) H[i] = cvt8v(R[2*i], R[2*i+1]);  // data-dep waits loads (W older -> also done)

#pragma unroll 1
    for (int kb = 0; kb < 12; ++kb) {
      _Float16* bufc = (kb & 1) ? b1 : b0;
      _Float16* bufn = (kb & 1) ? b0 : b1;
      _Float16* idst = imgb + (size_t)kb * TILE_HALFS;
      // commit current tile: LDS + image
#pragma unroll
      for (int i = 0; i < 4; ++i) {
        int e = (tid + i*256) * 8;
        *(f16x8*)(bufc + e) = H[i];                  // ds_write_b128
        *(f16x8*)(idst + e) = H[i];                  // global_store (image)
      }
      // issue next tile's W gloads + A fp32 loads (latency hides under MFMA below)
      if (kb < 11) {
#pragma unroll
        for (int i = 0; i < 4; ++i) {
          int e = (tid + i*256) * 8;
          gload_lds16(wb0 + (size_t)(kb+1)*TILE_HALFS + e, bufn + 8192 + e);
        }
        const float* an = asrc + (size_t)(kb+1) * BK;
#pragma unroll
        for (int i = 0; i < 4; ++i) {
          const float* p = an + (size_t)(32*i) * H_DIM;
          R[2*i] = *(const f32x4*)p; R[2*i+1] = *(const f32x4*)(p + 4);
        }
      }
      asm volatile("s_waitcnt lgkmcnt(0)" ::: "memory");  // ds_writes committed
      SBAR();                                             // W(kb) landed (in-order: older than consumed A(kb))
      rd_frags(bufc, aoff, boff, slot0, af0, bf0);
      mfma16(af0, bf0, acc);
      rd_frags(bufc, aoff, boff, slot1, af1, bf1);
      mfma16(af1, bf1, acc);
      if (kb < 11) {
#pragma unroll
        for (int i = 0; i < 4; ++i) H[i] = cvt8v(R[2*i], R[2*i+1]);  // waits A(kb+1)
      }
      SBAR();                                             // protect bufn.B from next iter's gloads
    }
  }

  // ================= transition: prologue of pass 1 under EPI(0) =================
  const _Float16* w1b = W16 + (size_t)((nb0 + 1) * KB_CNT) * TILE_HALFS;
  stage128(abase,              w1b,              b0, tid);
  stage128(abase + TILE_HALFS, w1b + TILE_HALFS, b1, tid);
  const _Float16* wS = w1b + 2 * TILE_HALFS;      // monotonic W stage cursor
  EPI(0);
#pragma unroll
  for (int mi = 0; mi < 4; ++mi)
#pragma unroll
    for (int ni = 0; ni < 4; ++ni) acc[mi][ni] = f32x4{0.f, 0.f, 0.f, 0.f};
  asm volatile("s_waitcnt vmcnt(8)" ::: "memory");  // pass-0 stores + t0 landed (t1's 8 in flight)
  SBAR();
  rd_frags(b0, aoff, boff, slot0, af0, bf0);        // pass-1 t0 kk0

  // ---- pass 1 ----
#pragma unroll 1
  for (int j = 0; j < 12; ++j) PASS_ITER(1, j);
  EPI(1);
#pragma unroll
  for (int mi = 0; mi < 4; ++mi)
#pragma unroll
    for (int ni = 0; ni < 4; ++ni) acc[mi][ni] = f32x4{0.f, 0.f, 0.f, 0.f};

  // ---- pass 2 (last tile peeled) ----
#pragma unroll 1
  for (int j = 0; j < 11; ++j) PASS_ITER(2, j);
  rd_frags(b1, aoff, boff, slot1, af1, bf1);        // t11 kk1
  mfma16(af0, bf0, acc);                            // t11 kk0
  mfma16(af1, bf1, acc);                            // t11 kk1
  EPI(2);
}

// ---------------- kernel 3: softmax over L per batch ----------------
__global__ __launch_bounds__(512) void softmax_kernel(const float* __restrict__ nup,
                                                      float* __restrict__ alphas) {
  int b = blockIdx.x;
  int l = threadIdx.x;
  int m = b * L_DIM + l;
  float v = 0.f;
  for (int nb = 0; nb < NB_CNT; ++nb) v += nup[(size_t)nb * M_TOT + m];
  __shared__ float smax[8], ssum[8];
  int w = l >> 6, ln = l & 63;
  float mx = v;
  for (int o = 1; o < 64; o <<= 1) mx = fmaxf(mx, __shfl_xor(mx, o, 64));
  if (ln == 0) smax[w] = mx;
  __syncthreads();
  mx = smax[0];
  for (int i = 1; i < 8; ++i) mx = fmaxf(mx, smax[i]);
  float e = __expf(v - mx);
  float sm = e;
  for (int o = 1; o < 64; o <<= 1) sm += __shfl_xor(sm, o, 64);
  if (ln == 0) ssum[w] = sm;
  __syncthreads();
  float tot = 0.f;
  for (int i = 0; i < 8; ++i) tot += ssum[i];
  alphas[m] = e / tot;
}

// ---------------- pooling from fp16 A-image (384 thr: 12 waves/CU, was 1.5) ------
__global__ __launch_bounds__(384) void pool1_img_kernel(const _Float16* __restrict__ img,
                                                        const float* __restrict__ alphas,
                                                        float* __restrict__ part) {
  int b = blockIdx.x >> 3;
  int lc = blockIdx.x & 7;
  int tid = threadIdx.x;
  int g = tid % 96, rp = tid / 96;      // rp in 0..3 (4-way row-parity)
  int kb = g >> 3, sl = g & 7;
  __shared__ float al[64];
  __shared__ float tmp[4][H_DIM];
  if (tid < 64) al[tid] = alphas[b * L_DIM + lc*64 + tid];
  __syncthreads();
  float s[8] = {};
  for (int l = rp; l < 64; l += 4) {    // 16 iterations per thread
    int m = b * L_DIM + lc*64 + l;
    int mb = m >> 7, row = m & 127;
    f16x8 h = *(const f16x8*)(img + ((size_t)(mb*KB_CNT + kb))*TILE_HALFS
                              + row*64 + ((sl ^ (row & 7)) * 8));
    float a = al[l];
#pragma unroll
    for (int j = 0; j < 8; ++j) s[j] = fmaf(a, (float)h[j], s[j]);
  }
#pragma unroll
  for (int j = 0; j < 8; ++j) tmp[rp][g*8 + j] = s[j];
  __syncthreads();
  if (tid < 192) {
    float* dst = part + ((size_t)lc * B_DIM + b) * H_DIM + tid*4;
    f32x4 o;
#pragma unroll
    for (int q = 0; q < 4; ++q)
      o[q] = (tmp[0][tid*4 + q] + tmp[1][tid*4 + q]) +
             (tmp[2][tid*4 + q] + tmp[3][tid*4 + q]);
    *(f32x4*)dst = o;
  }
}

__global__ __launch_bounds__(256) void pool2_kernel(const float* __restrict__ part,
                                                    float* __restrict__ out) {
  int i = blockIdx.x * 256 + threadIdx.x;
  float s = 0.f;
  for (int lc = 0; lc < 8; ++lc) s += part[(size_t)lc * (B_DIM * H_DIM) + i];
  out[i] = s;
}

extern "C" void kernel_launch(void* const* d_in, const int* in_sizes, int n_in,
                              void* d_out, int out_size, void* d_ws, size_t ws_size,
                              hipStream_t stream) {
  const float* hs  = (const float*)d_in[0];
  const float* Wfc = (const float*)d_in[1];
  const float* bfc = (const float*)d_in[2];
  const float* wnu = (const float*)d_in[3];
  float* out = (float*)d_out;
  char* ws = (char*)d_ws;
  _Float16* W16 = (_Float16*)(ws + WS_W16);
  float* nup    = (float*)(ws + WS_NUP);
  float* alphas = (float*)(ws + WS_ALPHA);
  float* part   = (float*)(ws + WS_POOL);
  _Float16* Aimg = (_Float16*)(ws + WS_AIMG);

  wconv_kernel<<<NB_CNT * KB_CNT, 256, 0, stream>>>(Wfc, W16);
  gemm_fused_kernel<<<MB_CNT * 2, 256, 0, stream>>>(hs, W16, bfc, wnu, Aimg, nup);
  softmax_kernel<<<B_DIM, 512, 0, stream>>>(nup, alphas);
  pool1_img_kernel<<<B_DIM * 8, 384, 0, stream>>>(Aimg, alphas, part);
  pool2_kernel<<<192, 256, 0, stream>>>(part, out);
}